// Round 7
// baseline (230.073 us; speedup 1.0000x reference)
//
#include <hip/hip_runtime.h>
#include <math.h>

// loss = mean_b[ 0.5*nrmse(o1,t1) + 0.25*nrmse(o2,t2) + 0.25*nrmse(o3,t3) ]
// B=4096 rows, N=2048 fp32. 201.3 MB in, 4 B out. Roofline ~32 us @6.3 TB/s.
//
// R1:  compiler-serialized loads, 74 us (2.8 TB/s app-side).
// R5:  asm 16-load burst, 71 us. R1 vs R5: 6x more in-flight bytes, SAME
//      2.8 TB/s -> service-rate saturated, NOT parallelism-starved.
// R6:  persistent pipeline confounded by spill (launch_bounds cap, VGPR=80,
//      WRITE_SIZE 96KB->20.7MB scratch traffic). No information.
// R7:  restructure to the PROVEN-fast shape on this machine (m146 row-reduce
//      4.9 TB/s): per-THREAD sequential loads, running scalar reduction,
//      ZERO cross-lane ops / ZERO drains in the hot loop. Lane l of a wave
//      owns row g*64+l over a 128-col segment; 16 segments/row; partials to
//      ws; stage2 combines. 4 back-to-back float4 loads per 64B line so
//      each line is MSHR-merged/fetched once despite the 8KB lane stride.
constexpr int N_ELEM   = 2048;
constexpr int BATCH    = 4096;
constexpr int ROWS     = 3 * BATCH;            // 12288 (pair-major)
constexpr int SEG      = 16;                   // column segments per row
constexpr int SEG_COLS = N_ELEM / SEG;         // 128 floats = 32 float4
constexpr int BLOCK    = 256;                  // 4 waves/block
constexpr int WTASKS   = (ROWS / 64) * SEG;    // 3072 wave-tasks
constexpr int GRID1    = WTASKS / (BLOCK / 64);// 768 blocks
// Workspace: pssd | pmax | pmin, each SEG*ROWS floats -> 2.36 MB total.

__global__ __launch_bounds__(BLOCK)
void wnrmse_stage1(const float* __restrict__ o1, const float* __restrict__ t1,
                   const float* __restrict__ o2, const float* __restrict__ t2,
                   const float* __restrict__ o3, const float* __restrict__ t3,
                   float* __restrict__ pssd, float* __restrict__ pmax,
                   float* __restrict__ pmin)
{
    const int tid  = threadIdx.x;
    const int wave = tid >> 6;
    const int lane = tid & 63;
    const int w    = blockIdx.x * (BLOCK / 64) + wave;  // 0..3071
    const int g    = w >> 4;          // rowgroup 0..191 (64 rows each)
    const int s    = w & (SEG - 1);   // segment 0..15 (block covers 4 segs of one g)
    const int r    = g * 64 + lane;   // global row 0..12287 (this thread's row)
    const int pair = g >> 6;          // wave-uniform (64 | 4096)
    const int row  = r & (BATCH - 1);

    const float* ob = (pair == 0) ? o1 : ((pair == 1) ? o2 : o3);
    const float* tb = (pair == 0) ? t1 : ((pair == 1) ? t2 : t3);

    const float4* o4 = (const float4*)(ob + (size_t)row * N_ELEM + s * SEG_COLS);
    const float4* t4 = (const float4*)(tb + (size_t)row * N_ELEM + s * SEG_COLS);

    float ssd0 = 0.0f, ssd1 = 0.0f;
    float mx0 = -INFINITY, mx1 = -INFINITY;
    float mn0 =  INFINITY, mn1 =  INFINITY;

    // 32 float4 per thread, grouped 4-per-64B-line so the 4 same-line loads
    // issue back-to-back (MSHR merge; line fetched once even under L1
    // pressure from other waves).
#pragma unroll
    for (int jg = 0; jg < SEG_COLS / 16; ++jg) {       // 8 line-groups
        float4 a0 = o4[4 * jg + 0], a1 = o4[4 * jg + 1];
        float4 a2 = o4[4 * jg + 2], a3 = o4[4 * jg + 3];
        float4 b0 = t4[4 * jg + 0], b1 = t4[4 * jg + 1];
        float4 b2 = t4[4 * jg + 2], b3 = t4[4 * jg + 3];
#define ACC1(AV, BV)                                              \
        {                                                         \
            float d0 = AV.x - BV.x, d1 = AV.y - BV.y;             \
            float d2 = AV.z - BV.z, d3 = AV.w - BV.w;             \
            ssd0 += d0 * d0 + d1 * d1;                            \
            ssd1 += d2 * d2 + d3 * d3;                            \
            mx0 = fmaxf(mx0, fmaxf(BV.x, BV.y));                  \
            mx1 = fmaxf(mx1, fmaxf(BV.z, BV.w));                  \
            mn0 = fminf(mn0, fminf(BV.x, BV.y));                  \
            mn1 = fminf(mn1, fminf(BV.z, BV.w));                  \
        }
        ACC1(a0, b0) ACC1(a1, b1) ACC1(a2, b2) ACC1(a3, b3)
#undef ACC1
    }

    // Coalesced partial stores: lane l -> row g*64+l (consecutive).
    pssd[s * ROWS + r] = ssd0 + ssd1;
    pmax[s * ROWS + r] = fmaxf(mx0, mx1);
    pmin[s * ROWS + r] = fminf(mn0, mn1);
}

// Stage 2: one block (1024 threads) combines SEG partials per row, computes
// weighted nrmse, reduces to the final scalar. 2.36 MB read, L2-resident.
__global__ __launch_bounds__(1024)
void wnrmse_stage2(const float* __restrict__ pssd, const float* __restrict__ pmax,
                   const float* __restrict__ pmin, float* __restrict__ out)
{
    const int tid = threadIdx.x;
    float acc = 0.0f;
    for (int r = tid; r < ROWS; r += 1024) {       // 12 rows/thread
        float ssd = 0.0f, mx = -INFINITY, mn = INFINITY;
#pragma unroll
        for (int s2 = 0; s2 < SEG; ++s2) {         // coalesced across threads
            ssd += pssd[s2 * ROWS + r];
            mx   = fmaxf(mx, pmax[s2 * ROWS + r]);
            mn   = fminf(mn, pmin[s2 * ROWS + r]);
        }
        const float wgt = ((r >> 12) == 0) ? 0.50f : 0.25f;
        acc += wgt * sqrtf(ssd * (1.0f / (float)N_ELEM)) / (mx - mn);
    }

    // 1024 -> 1: wave butterfly, then first wave folds the 16 wave-partials.
#pragma unroll
    for (int off = 32; off > 0; off >>= 1) acc += __shfl_xor(acc, off, 64);
    __shared__ float sp[16];
    if ((tid & 63) == 0) sp[tid >> 6] = acc;
    __syncthreads();
    if (tid < 16) {
        float v = sp[tid];
#pragma unroll
        for (int off = 8; off > 0; off >>= 1) v += __shfl_xor(v, off, 16);
        if (tid == 0) out[0] = v * (1.0f / (float)BATCH);
    }
}

extern "C" void kernel_launch(void* const* d_in, const int* in_sizes, int n_in,
                              void* d_out, int out_size, void* d_ws, size_t ws_size,
                              hipStream_t stream) {
    const float* o1 = (const float*)d_in[0];
    const float* t1 = (const float*)d_in[1];
    const float* o2 = (const float*)d_in[2];
    const float* t2 = (const float*)d_in[3];
    const float* o3 = (const float*)d_in[4];
    const float* t3 = (const float*)d_in[5];
    float* out  = (float*)d_out;
    float* pssd = (float*)d_ws;                    // SEG*ROWS floats
    float* pmax = pssd + SEG * ROWS;
    float* pmin = pmax + SEG * ROWS;               // total 2.36 MB, overwritten

    wnrmse_stage1<<<GRID1, BLOCK, 0, stream>>>(o1, t1, o2, t2, o3, t3,
                                               pssd, pmax, pmin);
    wnrmse_stage2<<<1, 1024, 0, stream>>>(pssd, pmax, pmin, out);
}

// Round 8
// 211.118 us; speedup vs baseline: 1.0898x; 1.0898x over previous
//
#include <hip/hip_runtime.h>
#include <math.h>

// loss = mean_b[ 0.5*nrmse(o1,t1) + 0.25*nrmse(o2,t2) + 0.25*nrmse(o3,t3) ]
// B=4096 rows, N=2048 fp32. 201.3 MB in, 4 B out.
//
// R1:  serialized loads, 74 us (2.8 TB/s read).
// R5:  asm 16-load burst, 71 us. Same rate as R1 despite 6x in-flight bytes.
// R6:  persistent pipeline VOIDED by spill (4 live sets under VGPR cap 80;
//      WRITE_SIZE 20.7 MB scratch).
// R7:  per-thread scattered streaming, 80 us (64 lines/instr TA cost).
// => three independent structures pin at ~2.8 TB/s read. Model: per-direction
//    XCD<->fabric cap ~3.2 TB/s aggregate (m13 copy 6.29 = 3.15/dir; m146
//    4.89 = 2.45/dir; us 2.8/dir read-only). Floor = 201.3MB/3.2 ~ 63 us.
// R8:  R6 done right: 2 burst-sets, depth-2, NO launch_bounds cap, 4 tasks
//      per wave, counted vmcnt(16) -> continuous issue, drains only at end.
//      Tests the last duty-cycle hypothesis + recovers ramp/drain slack.
constexpr int N_ELEM = 2048;
constexpr int BATCH  = 4096;
constexpr int BLOCK  = 256;                 // 4 waves/block
constexpr int TASKS  = 3 * BATCH;           // 12288 (pair,row) tasks
constexpr int GRID1  = 768;                 // 3072 waves, 4 tasks/wave
constexpr int WAVES  = GRID1 * (BLOCK/64);
static_assert(TASKS % WAVES == 0, "tasks must divide evenly");

typedef float f32x4 __attribute__((ext_vector_type(4)));

// 16 coalesced dwordx4 loads (8 KB o + 8 KB t of one row), NO waitcnt inside:
// completion claimed later via counted vmcnt. "=&v" early-clobber required
// (load returns race the address inputs otherwise — R3 lesson).
#define DECL_SET(P) f32x4 P##o0,P##o1,P##o2,P##o3,P##o4,P##o5,P##o6,P##o7, \
                          P##t0,P##t1,P##t2,P##t3,P##t4,P##t5,P##t6,P##t7;

#define BURST(P, K)                                                         \
    asm volatile(                                                           \
        "global_load_dwordx4 %0,  %[olo], off\n\t"                          \
        "global_load_dwordx4 %1,  %[olo], off offset:1024\n\t"              \
        "global_load_dwordx4 %2,  %[olo], off offset:2048\n\t"              \
        "global_load_dwordx4 %3,  %[olo], off offset:3072\n\t"              \
        "global_load_dwordx4 %4,  %[ohi], off\n\t"                          \
        "global_load_dwordx4 %5,  %[ohi], off offset:1024\n\t"              \
        "global_load_dwordx4 %6,  %[ohi], off offset:2048\n\t"              \
        "global_load_dwordx4 %7,  %[ohi], off offset:3072\n\t"              \
        "global_load_dwordx4 %8,  %[tlo], off\n\t"                          \
        "global_load_dwordx4 %9,  %[tlo], off offset:1024\n\t"              \
        "global_load_dwordx4 %10, %[tlo], off offset:2048\n\t"              \
        "global_load_dwordx4 %11, %[tlo], off offset:3072\n\t"              \
        "global_load_dwordx4 %12, %[thi], off\n\t"                          \
        "global_load_dwordx4 %13, %[thi], off offset:1024\n\t"              \
        "global_load_dwordx4 %14, %[thi], off offset:2048\n\t"              \
        "global_load_dwordx4 %15, %[thi], off offset:3072"                  \
        : "=&v"(P##o0), "=&v"(P##o1), "=&v"(P##o2), "=&v"(P##o3),           \
          "=&v"(P##o4), "=&v"(P##o5), "=&v"(P##o6), "=&v"(P##o7),           \
          "=&v"(P##t0), "=&v"(P##t1), "=&v"(P##t2), "=&v"(P##t3),           \
          "=&v"(P##t4), "=&v"(P##t5), "=&v"(P##t6), "=&v"(P##t7)            \
        : [olo] "v"(K.olo), [ohi] "v"(K.ohi),                               \
          [tlo] "v"(K.tlo), [thi] "v"(K.thi)                                \
        : "memory");

// Counted waits + sched_barrier(0) (rule 18: hipcc hoists register-only ops
// past inline-asm waitcnt despite "memory").
#define WAITV16 asm volatile("s_waitcnt vmcnt(16)" ::: "memory"); \
                __builtin_amdgcn_sched_barrier(0);
#define WAITV0  asm volatile("s_waitcnt vmcnt(0)"  ::: "memory"); \
                __builtin_amdgcn_sched_barrier(0);

#define ACC(OV, TV)                                                  \
    {                                                                \
        float d0 = OV[0] - TV[0];                                    \
        float d1 = OV[1] - TV[1];                                    \
        float d2 = OV[2] - TV[2];                                    \
        float d3 = OV[3] - TV[3];                                    \
        ssd0 += d0 * d0 + d1 * d1;                                   \
        ssd1 += d2 * d2 + d3 * d3;                                   \
        tmax0 = fmaxf(tmax0, fmaxf(TV[0], TV[1]));                   \
        tmax1 = fmaxf(tmax1, fmaxf(TV[2], TV[3]));                   \
        tmin0 = fminf(tmin0, fminf(TV[0], TV[1]));                   \
        tmin1 = fminf(tmin1, fminf(TV[2], TV[3]));                   \
    }

// Per-row statistic: accumulate, wave-64 butterfly, add weighted nrmse.
#define ROWSTAT(P, W)                                                       \
    {                                                                       \
        float ssd0 = 0.0f, ssd1 = 0.0f;                                     \
        float tmax0 = -INFINITY, tmax1 = -INFINITY;                         \
        float tmin0 =  INFINITY, tmin1 =  INFINITY;                         \
        ACC(P##o0, P##t0) ACC(P##o1, P##t1) ACC(P##o2, P##t2)               \
        ACC(P##o3, P##t3) ACC(P##o4, P##t4) ACC(P##o5, P##t5)               \
        ACC(P##o6, P##t6) ACC(P##o7, P##t7)                                 \
        float ssd  = ssd0 + ssd1;                                           \
        float tmax = fmaxf(tmax0, tmax1);                                   \
        float tmin = fminf(tmin0, tmin1);                                   \
        _Pragma("unroll")                                                   \
        for (int off = 32; off > 0; off >>= 1) {                            \
            ssd  += __shfl_xor(ssd, off, 64);                               \
            tmax  = fmaxf(tmax, __shfl_xor(tmax, off, 64));                 \
            tmin  = fminf(tmin, __shfl_xor(tmin, off, 64));                 \
        }                                                                   \
        local += (W) * sqrtf(ssd * (1.0f / (float)N_ELEM)) / (tmax - tmin); \
    }

__global__ __launch_bounds__(BLOCK)   // NO min-waves arg: let VGPRs float (~165)
void wnrmse_stage1(const float* __restrict__ o1, const float* __restrict__ t1,
                   const float* __restrict__ o2, const float* __restrict__ t2,
                   const float* __restrict__ o3, const float* __restrict__ t3,
                   float* __restrict__ partial)
{
    const int tid  = threadIdx.x;
    const int wave = tid >> 6;
    const int lane = tid & 63;
    const int gw   = blockIdx.x * (BLOCK / 64) + wave;   // 0..3071

    struct Addr { const float* olo; const float* ohi;
                  const float* tlo; const float* thi; float w; };
    auto decode = [&](int task, Addr& a) {
        const int pair = task >> 12;          // wave-uniform
        const int row  = task & (BATCH - 1);
        const float* ob = (pair == 0) ? o1 : ((pair == 1) ? o2 : o3);
        const float* tb = (pair == 0) ? t1 : ((pair == 1) ? t2 : t3);
        a.olo = ob + (size_t)row * N_ELEM + lane * 4;
        a.ohi = a.olo + 1024;                 // +4096 bytes
        a.tlo = tb + (size_t)row * N_ELEM + lane * 4;
        a.thi = a.tlo + 1024;
        a.w   = (pair == 0) ? 0.50f : 0.25f;
    };

    float local = 0.0f;
    DECL_SET(A) DECL_SET(B)    // exactly 2 live sets -> ~128 data VGPRs

    Addr k0, k1, k2, k3;
    decode(gw,             k0);
    decode(gw + WAVES,     k1);
    decode(gw + 2 * WAVES, k2);
    decode(gw + 3 * WAVES, k3);

    BURST(A, k0)        // 16 outstanding
    BURST(B, k1)        // 32 outstanding

    WAITV16             // A complete; B's 16 still in flight
    ROWSTAT(A, k0.w)
    BURST(A, k2)        // back to 32 outstanding — never idle

    WAITV16             // B complete; A(k2) in flight
    ROWSTAT(B, k1.w)
    BURST(B, k3)

    WAITV16             // A(k2) complete
    ROWSTAT(A, k2.w)

    WAITV0              // last task
    ROWSTAT(B, k3.w)

    // Per-block combine, one plain store per block.
    __shared__ float s_part[BLOCK / 64];
    if (lane == 0) s_part[wave] = local;
    __syncthreads();
    if (tid == 0) {
        partial[blockIdx.x] = s_part[0] + s_part[1] + s_part[2] + s_part[3];
    }
}

// Stage 2: one block reduces GRID1 partials and writes the final scalar.
__global__ __launch_bounds__(BLOCK)
void wnrmse_stage2(const float* __restrict__ partial, float* __restrict__ out)
{
    const int tid = threadIdx.x;
    float s = 0.0f;
    for (int i = tid; i < GRID1; i += BLOCK) s += partial[i];

#pragma unroll
    for (int off = 32; off > 0; off >>= 1) s += __shfl_xor(s, off, 64);

    __shared__ float s_part[BLOCK / 64];
    const int wave = tid >> 6;
    const int lane = tid & 63;
    if (lane == 0) s_part[wave] = s;
    __syncthreads();
    if (tid == 0) {
        float tot = s_part[0] + s_part[1] + s_part[2] + s_part[3];
        out[0] = tot * (1.0f / (float)BATCH);
    }
}

extern "C" void kernel_launch(void* const* d_in, const int* in_sizes, int n_in,
                              void* d_out, int out_size, void* d_ws, size_t ws_size,
                              hipStream_t stream) {
    const float* o1 = (const float*)d_in[0];
    const float* t1 = (const float*)d_in[1];
    const float* o2 = (const float*)d_in[2];
    const float* t2 = (const float*)d_in[3];
    const float* o3 = (const float*)d_in[4];
    const float* t3 = (const float*)d_in[5];
    float* out     = (float*)d_out;
    float* partial = (float*)d_ws;    // GRID1 floats = 3 KiB, fully overwritten

    wnrmse_stage1<<<GRID1, BLOCK, 0, stream>>>(o1, t1, o2, t2, o3, t3, partial);
    wnrmse_stage2<<<1, BLOCK, 0, stream>>>(partial, out);
}